// Round 3
// baseline (100.912 us; speedup 1.0000x reference)
//
#include <hip/hip_runtime.h>
#include <hip/hip_fp16.h>

typedef _Float16 f16x8 __attribute__((ext_vector_type(8)));
typedef float f32x4 __attribute__((ext_vector_type(4)));

// ---------------------------------------------------------------------------
// prep_all: blocks 0-2047 cvt source->f16; 2048-4095 cvt target->f16;
//           4096-4223 build WcT [128][256] f16, Wt16 [64][256] f16, bmean[64]
// ---------------------------------------------------------------------------
__global__ void prep_all(const float* __restrict__ source, const float* __restrict__ target,
                         const float* __restrict__ W_lin, const float* __restrict__ b_lin,
                         const float* __restrict__ W_s, const float* __restrict__ W_t,
                         _Float16* __restrict__ src16, _Float16* __restrict__ tgt16,
                         _Float16* __restrict__ WcT, _Float16* __restrict__ Wt16,
                         float* __restrict__ bmean) {
    int b = blockIdx.x;
    if (b < 4096) {
        const float* s = (b < 2048) ? source : target;
        _Float16* d = (b < 2048) ? src16 : tgt16;
        int i = ((b & 2047) * 256 + threadIdx.x) * 8;
        f32x4 x = *(const f32x4*)(s + i);
        f32x4 y = *(const f32x4*)(s + i + 4);
        f16x8 h;
        h[0] = (_Float16)x[0]; h[1] = (_Float16)x[1]; h[2] = (_Float16)x[2]; h[3] = (_Float16)x[3];
        h[4] = (_Float16)y[0]; h[5] = (_Float16)y[1]; h[6] = (_Float16)y[2]; h[7] = (_Float16)y[3];
        *(f16x8*)(d + i) = h;
        return;
    }
    int tid = (b - 4096) * 256 + threadIdx.x;    // 32768 threads
    if (tid < 16384) {
        int c = tid >> 6, o = tid & 63;
        WcT[o * 256 + c]  = (_Float16)W_s[c * 64 + o];
        Wt16[o * 256 + c] = (_Float16)W_t[c * 64 + o];
    } else {
        int t = tid - 16384;
        int c = t >> 6, o = t & 63;
        float s = 0.f;
        #pragma unroll 8
        for (int m = 0; m < 64; ++m) s += W_lin[m * 16384 + c * 64 + o];
        WcT[(64 + o) * 256 + c] = (_Float16)(s * (1.f / 64.f));
    }
    if (tid < 64) {
        float s = 0.f;
        #pragma unroll 8
        for (int m = 0; m < 64; ++m) s += b_lin[m * 64 + tid];
        bmean[tid] = s * (1.f / 64.f);
    }
}

// ---------------------------------------------------------------------------
// prep_tl: tl[n][m] = target . W_t + b_s + b_t  via MFMA (64 blocks x 256)
// ---------------------------------------------------------------------------
__global__ __launch_bounds__(256, 4)
void prep_tl(const _Float16* __restrict__ tgt16, const _Float16* __restrict__ Wt16,
             const float* __restrict__ b_s, const float* __restrict__ b_t,
             float* __restrict__ tl) {
    __shared__ _Float16 lds[16384];

    const int tid = threadIdx.x;
    const int w = tid >> 6, l = tid & 63;
    const int l15 = l & 15, lq = l >> 4;
    const int rowbase = blockIdx.x * 256 + w * 64;

    const _Float16* ap[4];
    f16x8 ac[4];
    #pragma unroll
    for (int m = 0; m < 4; ++m) {
        ap[m] = tgt16 + (size_t)(rowbase + m * 16 + l15) * 256 + lq * 8;
        ac[m] = *(const f16x8*)ap[m];
    }
    #pragma unroll
    for (int i = 0; i < 8; ++i) {
        int fi = i * 4 + w;
        int nt = fi >> 3, s = fi & 7;
        f16x8 v = *(const f16x8*)(Wt16 + (nt * 16 + l15) * 256 + s * 32 + lq * 8);
        *(f16x8*)((char*)lds + (i * 256 + tid) * 16) = v;
    }
    __syncthreads();

    const char* bb = (const char*)lds + l * 16;
    f32x4 acc[4][4] = {};
    #pragma unroll
    for (int s = 0; s < 8; ++s) {
        f16x8 an[4];
        if (s < 7) {
            #pragma unroll
            for (int m = 0; m < 4; ++m) an[m] = *(const f16x8*)(ap[m] + (s + 1) * 32);
        }
        #pragma unroll
        for (int nt = 0; nt < 4; ++nt) {
            f16x8 bfr = *(const f16x8*)(bb + nt * 8192 + s * 1024);
            #pragma unroll
            for (int m = 0; m < 4; ++m)
                acc[m][nt] = __builtin_amdgcn_mfma_f32_16x16x32_f16(ac[m], bfr, acc[m][nt], 0, 0, 0);
        }
        if (s < 7) {
            #pragma unroll
            for (int m = 0; m < 4; ++m) ac[m] = an[m];
        }
    }

    float bsv[4];
    #pragma unroll
    for (int nt = 0; nt < 4; ++nt) {
        int col = nt * 16 + l15;
        bsv[nt] = b_s[col] + b_t[col];
    }
    #pragma unroll
    for (int m = 0; m < 4; ++m)
        #pragma unroll
        for (int j = 0; j < 4; ++j) {
            int r = rowbase + m * 16 + lq * 4 + j;
            #pragma unroll
            for (int nt = 0; nt < 4; ++nt)
                tl[r * 64 + nt * 16 + l15] = acc[m][nt][j] + bsv[nt];
        }
}

// ---------------------------------------------------------------------------
// main: persistent 512 blocks x 512 thr; each block does 4 row-tiles of 256.
// B (64 KiB) staged once, fragment-major; one barrier total.
// A gather: 2-step-granule double buffer + cross-tile prefetch.
// ---------------------------------------------------------------------------
#define LD(p, s) (*(const f16x8*)((p) + (s) * 32))

#define MM2(S, A0, A1)                                                          \
    _Pragma("unroll")                                                           \
    for (int nt = 0; nt < 8; ++nt) {                                            \
        f16x8 bfr = *(const f16x8*)(bb + nt * 8192 + (S) * 1024);               \
        acc[0][nt] = __builtin_amdgcn_mfma_f32_16x16x32_f16(A0, bfr, acc[0][nt], 0, 0, 0); \
        acc[1][nt] = __builtin_amdgcn_mfma_f32_16x16x32_f16(A1, bfr, acc[1][nt], 0, 0, 0); \
    }

__global__ __launch_bounds__(512, 4)
void main_kernel(const _Float16* __restrict__ src16, const int* __restrict__ neighbors,
                 const _Float16* __restrict__ WcT, const float* __restrict__ tl,
                 const float* __restrict__ bmean, float* __restrict__ out) {
    __shared__ _Float16 lds[32768];   // 64 KiB B, fragment-major

    const int tid = threadIdx.x;
    const int w = tid >> 6, l = tid & 63;
    const int l15 = l & 15, lq = l >> 4;
    const int rowbase = blockIdx.x * 256 + w * 32;
    const int r0 = rowbase + l15;
    const int r1 = rowbase + 16 + l15;

    // tile-0 neighbor indices + first 2 K-steps of A (in flight during staging)
    int nb0 = neighbors[r0];
    int nb1 = neighbors[r1];
    const _Float16* ap0 = src16 + (size_t)nb0 * 256 + lq * 8;
    const _Float16* ap1 = src16 + (size_t)nb1 * 256 + lq * 8;
    f16x8 c00 = LD(ap0, 0), c10 = LD(ap1, 0), c01 = LD(ap0, 1), c11 = LD(ap1, 1);

    // stage B fragment-major
    #pragma unroll
    for (int i = 0; i < 8; ++i) {
        int fi = i * 8 + w;
        int nt = fi >> 3, s = fi & 7;
        f16x8 v = *(const f16x8*)(WcT + (nt * 16 + l15) * 256 + s * 32 + lq * 8);
        *(f16x8*)((char*)lds + (i * 512 + tid) * 16) = v;
    }
    __syncthreads();

    const char* bb = (const char*)lds + l * 16;

    float bmv[4];
    #pragma unroll
    for (int nt = 0; nt < 4; ++nt) bmv[nt] = bmean[nt * 16 + l15];

    #pragma unroll
    for (int it = 0; it < 4; ++it) {
        f32x4 acc[2][8] = {};
        f16x8 n00, n01, n10, n11;
        int nbn0, nbn1;

        // pair 0: prefetch steps 2,3
        n00 = LD(ap0, 2); n10 = LD(ap1, 2); n01 = LD(ap0, 3); n11 = LD(ap1, 3);
        MM2(0, c00, c10)
        MM2(1, c01, c11)
        c00 = n00; c10 = n10; c01 = n01; c11 = n11;

        // pair 2: prefetch steps 4,5
        n00 = LD(ap0, 4); n10 = LD(ap1, 4); n01 = LD(ap0, 5); n11 = LD(ap1, 5);
        MM2(2, c00, c10)
        MM2(3, c01, c11)
        c00 = n00; c10 = n10; c01 = n01; c11 = n11;

        // pair 4: prefetch steps 6,7 + next tile's neighbor indices
        n00 = LD(ap0, 6); n10 = LD(ap1, 6); n01 = LD(ap0, 7); n11 = LD(ap1, 7);
        if (it < 3) {
            nbn0 = neighbors[r0 + (it + 1) * 131072];
            nbn1 = neighbors[r1 + (it + 1) * 131072];
        }
        MM2(4, c00, c10)
        MM2(5, c01, c11)
        c00 = n00; c10 = n10; c01 = n01; c11 = n11;

        // pair 6: issue next tile's steps 0,1
        const int n = (blockIdx.x + it * 512) * 8 + w;
        float tlv0 = tl[n * 64 + l15];
        float tlv1 = tl[n * 64 + 16 + l15];
        float tlv2 = tl[n * 64 + 32 + l15];
        float tlv3 = tl[n * 64 + 48 + l15];
        if (it < 3) {
            ap0 = src16 + (size_t)nbn0 * 256 + lq * 8;
            ap1 = src16 + (size_t)nbn1 * 256 + lq * 8;
            n00 = LD(ap0, 0); n10 = LD(ap1, 0); n01 = LD(ap0, 1); n11 = LD(ap1, 1);
        }
        MM2(6, c00, c10)
        MM2(7, c01, c11)
        if (it < 3) { c00 = n00; c10 = n10; c01 = n01; c11 = n11; }

        // epilogue: softmax over 64 logit cols, multiply proj, store
        const float tlv[4] = {tlv0, tlv1, tlv2, tlv3};
        const int rb = rowbase + it * 131072;
        #pragma unroll
        for (int m = 0; m < 2; ++m) {
            #pragma unroll
            for (int j = 0; j < 4; ++j) {
                const int r = rb + m * 16 + lq * 4 + j;
                float lg[4];
                float mx = -1e30f;
                #pragma unroll
                for (int nt = 0; nt < 4; ++nt) {
                    lg[nt] = acc[m][nt][j] + tlv[nt];
                    mx = fmaxf(mx, lg[nt]);
                }
                #pragma unroll
                for (int d = 1; d < 16; d <<= 1) mx = fmaxf(mx, __shfl_xor(mx, d));
                float e[4], sum = 0.f;
                #pragma unroll
                for (int nt = 0; nt < 4; ++nt) {
                    e[nt] = __expf(lg[nt] - mx);
                    sum += e[nt];
                }
                #pragma unroll
                for (int d = 1; d < 16; d <<= 1) sum += __shfl_xor(sum, d);
                const float inv = 1.0f / sum;
                float* orow = out + (size_t)r * 64;
                #pragma unroll
                for (int nt = 0; nt < 4; ++nt) {
                    float a = e[nt] * inv;
                    orow[nt * 16 + l15] = a * (acc[m][nt + 4][j] + bmv[nt]);
                }
            }
        }
    }
}

// ---------------------------------------------------------------------------
extern "C" void kernel_launch(void* const* d_in, const int* in_sizes, int n_in,
                              void* d_out, int out_size, void* d_ws, size_t ws_size,
                              hipStream_t stream) {
    const float* source    = (const float*)d_in[0];
    const float* target    = (const float*)d_in[1];
    const int*   neighbors = (const int*)d_in[2];
    const float* W_lin     = (const float*)d_in[3];
    const float* b_lin     = (const float*)d_in[4];
    const float* W_s       = (const float*)d_in[5];
    const float* b_s       = (const float*)d_in[6];
    const float* W_t       = (const float*)d_in[7];
    const float* b_t       = (const float*)d_in[8];

    char* ws = (char*)d_ws;
    _Float16* src16 = (_Float16*)ws;                          // 8 MiB
    _Float16* tgt16 = (_Float16*)(ws + (8u << 20));           // 8 MiB
    _Float16* WcT   = (_Float16*)(ws + (16u << 20));          // 64 KiB
    _Float16* Wt16  = (_Float16*)(ws + (16u << 20) + 65536);  // 32 KiB
    float*    bmean = (float*)(ws + (16u << 20) + 98304);     // 256 B
    float*    tl    = (float*)(ws + (16u << 20) + 98560);     // 4 MiB
    float*    out   = (float*)d_out;

    prep_all<<<4224, 256, 0, stream>>>(source, target, W_lin, b_lin, W_s, W_t,
                                       src16, tgt16, WcT, Wt16, bmean);
    prep_tl<<<64, 256, 0, stream>>>(tgt16, Wt16, b_s, b_t, tl);
    main_kernel<<<512, 512, 0, stream>>>(src16, neighbors, WcT, tl, bmean, out);
}

// Round 4
// 55.432 us; speedup vs baseline: 1.8205x; 1.8205x over previous
//
#include <hip/hip_runtime.h>
#include <hip/hip_fp16.h>

typedef _Float16 f16x8 __attribute__((ext_vector_type(8)));
typedef _Float16 f16x4 __attribute__((ext_vector_type(4)));
typedef float f32x4 __attribute__((ext_vector_type(4)));

// ---------------------------------------------------------------------------
// prep_weights: 128 blocks x 256 threads
//   WcT  f16 [128][256]: row o<64 = W_s col o; row 64+o = mean_m W_lin col o
//   Wt16 f16 [64][256] : W_t transposed
//   bmean f32 [64]     : mean_m b_lin
// ---------------------------------------------------------------------------
__global__ void prep_weights(const float* __restrict__ W_lin, const float* __restrict__ b_lin,
                             const float* __restrict__ W_s, const float* __restrict__ W_t,
                             _Float16* __restrict__ WcT, _Float16* __restrict__ Wt16,
                             float* __restrict__ bmean) {
    int tid = blockIdx.x * 256 + threadIdx.x;    // 32768 threads
    if (tid < 16384) {
        int c = tid >> 6, o = tid & 63;
        WcT[o * 256 + c]  = (_Float16)W_s[c * 64 + o];
        Wt16[o * 256 + c] = (_Float16)W_t[c * 64 + o];
    } else {
        int t = tid - 16384;
        int c = t >> 6, o = t & 63;
        float s = 0.f;
        #pragma unroll 8
        for (int m = 0; m < 64; ++m) s += W_lin[m * 16384 + c * 64 + o];
        WcT[(64 + o) * 256 + c] = (_Float16)(s * (1.f / 64.f));
    }
    if (tid < 64) {
        float s = 0.f;
        #pragma unroll 8
        for (int m = 0; m < 64; ++m) s += b_lin[m * 64 + tid];
        bmean[tid] = s * (1.f / 64.f);
    }
}

// ---------------------------------------------------------------------------
// gemm_prep: 512 blocks x 256 threads (4 waves), 64 A-rows per block.
//  blocks 0..255  : Pe[r][o] = exp((source@W_s)[r][o])          f16
//                   Pp[r][o] = (source@W_mean)[r][o] + bmean[o] f16
//  blocks 256..511: Et[r][o] = exp((target@W_t)[r][o] + b_s[o] + b_t[o]) f32
//  A rows read f32 (full K upfront, 16 loads in flight), cvt f16 in-reg.
//  B staged fragment-major in LDS (conflict-free ds_read_b128 at l*16+imm).
// ---------------------------------------------------------------------------
__device__ __forceinline__ f16x8 cvt8(const float* p) {
    f32x4 x = *(const f32x4*)p;
    f32x4 y = *(const f32x4*)(p + 4);
    f16x8 h;
    h[0] = (_Float16)x[0]; h[1] = (_Float16)x[1]; h[2] = (_Float16)x[2]; h[3] = (_Float16)x[3];
    h[4] = (_Float16)y[0]; h[5] = (_Float16)y[1]; h[6] = (_Float16)y[2]; h[7] = (_Float16)y[3];
    return h;
}

__global__ __launch_bounds__(256, 2)
void gemm_prep(const float* __restrict__ source, const float* __restrict__ target,
               const _Float16* __restrict__ WcT, const _Float16* __restrict__ Wt16,
               const float* __restrict__ bmean, const float* __restrict__ b_s,
               const float* __restrict__ b_t,
               _Float16* __restrict__ Pe, _Float16* __restrict__ Pp,
               float* __restrict__ Et) {
    __shared__ _Float16 lds[32768];   // SRC path uses 64 KiB, TGT 32 KiB

    const int tid = threadIdx.x;
    const int w = tid >> 6, l = tid & 63;
    const int l15 = l & 15, lq = l >> 4;
    const int b = blockIdx.x;

    if (b < 256) {
        // ---------------- SRC path ----------------
        const int rb = b * 64;
        const float* arow = source + (size_t)(rb + w * 16 + l15) * 256;
        f16x8 af[8];
        #pragma unroll
        for (int s = 0; s < 8; ++s) af[s] = cvt8(arow + s * 32 + lq * 8);

        #pragma unroll
        for (int i = 0; i < 16; ++i) {
            int c = i * 256 + tid;                   // 4096 chunks
            int fi = c >> 6, lane = c & 63;
            int nt = fi >> 3, s = fi & 7;
            f16x8 v = *(const f16x8*)(WcT + (nt * 16 + (lane & 15)) * 256 + s * 32 + (lane >> 4) * 8);
            *(f16x8*)((char*)lds + c * 16) = v;
        }
        __syncthreads();

        const char* bb = (const char*)lds + l * 16;
        f32x4 acc[8] = {};
        #pragma unroll
        for (int s = 0; s < 8; ++s) {
            #pragma unroll
            for (int nt = 0; nt < 8; ++nt) {
                f16x8 bf = *(const f16x8*)(bb + nt * 8192 + s * 1024);
                acc[nt] = __builtin_amdgcn_mfma_f32_16x16x32_f16(af[s], bf, acc[nt], 0, 0, 0);
            }
        }

        float bmv[4];
        #pragma unroll
        for (int nt = 0; nt < 4; ++nt) bmv[nt] = bmean[nt * 16 + l15];
        #pragma unroll
        for (int j = 0; j < 4; ++j) {
            int row = rb + w * 16 + lq * 4 + j;
            #pragma unroll
            for (int nt = 0; nt < 4; ++nt) {
                Pe[row * 64 + nt * 16 + l15] = (_Float16)__expf(acc[nt][j]);
                Pp[row * 64 + nt * 16 + l15] = (_Float16)(acc[nt + 4][j] + bmv[nt]);
            }
        }
    } else {
        // ---------------- TGT path ----------------
        const int rb = (b - 256) * 64;
        const float* arow = target + (size_t)(rb + w * 16 + l15) * 256;
        f16x8 af[8];
        #pragma unroll
        for (int s = 0; s < 8; ++s) af[s] = cvt8(arow + s * 32 + lq * 8);

        #pragma unroll
        for (int i = 0; i < 8; ++i) {
            int c = i * 256 + tid;                   // 2048 chunks
            int fi = c >> 6, lane = c & 63;
            int nt = fi >> 3, s = fi & 7;
            f16x8 v = *(const f16x8*)(Wt16 + (nt * 16 + (lane & 15)) * 256 + s * 32 + (lane >> 4) * 8);
            *(f16x8*)((char*)lds + c * 16) = v;
        }
        __syncthreads();

        const char* bb = (const char*)lds + l * 16;
        f32x4 acc[4] = {};
        #pragma unroll
        for (int s = 0; s < 8; ++s) {
            #pragma unroll
            for (int nt = 0; nt < 4; ++nt) {
                f16x8 bf = *(const f16x8*)(bb + nt * 8192 + s * 1024);
                acc[nt] = __builtin_amdgcn_mfma_f32_16x16x32_f16(af[s], bf, acc[nt], 0, 0, 0);
            }
        }

        float bsv[4];
        #pragma unroll
        for (int nt = 0; nt < 4; ++nt) {
            int col = nt * 16 + l15;
            bsv[nt] = b_s[col] + b_t[col];
        }
        #pragma unroll
        for (int j = 0; j < 4; ++j) {
            int row = rb + w * 16 + lq * 4 + j;
            #pragma unroll
            for (int nt = 0; nt < 4; ++nt)
                Et[row * 64 + nt * 16 + l15] = __expf(acc[nt][j] + bsv[nt]);
        }
    }
}

// ---------------------------------------------------------------------------
// epilogue: 4096 blocks x 256 threads; one target node n per wave (32 rows).
// Lane (lq,l15): group g handles 4 rows (lq) x 4 cols (l15*4..+3).
// out[r][o] = Pe[nb][o]*Et[n][o] / sum_o(Pe*Et) * Pp[nb][o]
// ---------------------------------------------------------------------------
__global__ __launch_bounds__(256)
void epilogue(const int* __restrict__ neighbors, const _Float16* __restrict__ Pe,
              const _Float16* __restrict__ Pp, const float* __restrict__ Et,
              float* __restrict__ out) {
    const int tid = threadIdx.x;
    const int w = tid >> 6, l = tid & 63;
    const int lq = l >> 4, l15 = l & 15;
    const int n = blockIdx.x * 4 + w;
    const int co = l15 * 4;

    f32x4 et = *(const f32x4*)(Et + n * 64 + co);

    int nb[8];
    #pragma unroll
    for (int g = 0; g < 8; ++g) nb[g] = neighbors[n * 32 + g * 4 + lq];

    f16x4 pe[8], pp[8];
    #pragma unroll
    for (int g = 0; g < 2; ++g) {
        pe[g] = *(const f16x4*)(Pe + nb[g] * 64 + co);
        pp[g] = *(const f16x4*)(Pp + nb[g] * 64 + co);
    }

    #pragma unroll
    for (int g = 0; g < 8; ++g) {
        if (g + 2 < 8) {
            pe[g + 2] = *(const f16x4*)(Pe + nb[g + 2] * 64 + co);
            pp[g + 2] = *(const f16x4*)(Pp + nb[g + 2] * 64 + co);
        }
        float w0 = (float)pe[g][0] * et[0];
        float w1 = (float)pe[g][1] * et[1];
        float w2 = (float)pe[g][2] * et[2];
        float w3 = (float)pe[g][3] * et[3];
        float s = (w0 + w1) + (w2 + w3);
        s += __shfl_xor(s, 1);
        s += __shfl_xor(s, 2);
        s += __shfl_xor(s, 4);
        s += __shfl_xor(s, 8);
        float inv = 1.0f / s;
        f32x4 o;
        o[0] = w0 * inv * (float)pp[g][0];
        o[1] = w1 * inv * (float)pp[g][1];
        o[2] = w2 * inv * (float)pp[g][2];
        o[3] = w3 * inv * (float)pp[g][3];
        *(f32x4*)(out + (size_t)(n * 32 + g * 4 + lq) * 64 + co) = o;
    }
}

// ---------------------------------------------------------------------------
extern "C" void kernel_launch(void* const* d_in, const int* in_sizes, int n_in,
                              void* d_out, int out_size, void* d_ws, size_t ws_size,
                              hipStream_t stream) {
    const float* source    = (const float*)d_in[0];
    const float* target    = (const float*)d_in[1];
    const int*   neighbors = (const int*)d_in[2];
    const float* W_lin     = (const float*)d_in[3];
    const float* b_lin     = (const float*)d_in[4];
    const float* W_s       = (const float*)d_in[5];
    const float* b_s       = (const float*)d_in[6];
    const float* W_t       = (const float*)d_in[7];
    const float* b_t       = (const float*)d_in[8];

    char* ws = (char*)d_ws;
    _Float16* Pe    = (_Float16*)ws;                          // 2 MiB
    _Float16* Pp    = (_Float16*)(ws + (2u << 20));           // 2 MiB
    float*    Et    = (float*)(ws + (4u << 20));              // 4 MiB
    _Float16* WcT   = (_Float16*)(ws + (8u << 20));           // 64 KiB
    _Float16* Wt16  = (_Float16*)(ws + (8u << 20) + 65536);   // 32 KiB
    float*    bmean = (float*)(ws + (8u << 20) + 98304);      // 256 B
    float*    out   = (float*)d_out;

    prep_weights<<<128, 256, 0, stream>>>(W_lin, b_lin, W_s, W_t, WcT, Wt16, bmean);
    gemm_prep<<<512, 256, 0, stream>>>(source, target, WcT, Wt16, bmean, b_s, b_t,
                                       Pe, Pp, Et);
    epilogue<<<4096, 256, 0, stream>>>(neighbors, Pe, Pp, Et, out);
}